// Round 3
// baseline (321.800 us; speedup 1.0000x reference)
//
#include <hip/hip_runtime.h>
#include <hip/hip_bf16.h>
#include <stdint.h>

typedef float  f32x4  __attribute__((ext_vector_type(4)));
typedef short  bf16x8 __attribute__((ext_vector_type(8)));
typedef float  float4v __attribute__((ext_vector_type(4)));
typedef unsigned short ushort_t;
typedef ushort_t ushort4v __attribute__((ext_vector_type(4)));

#define BM 128
#define BN 128
#define BK 64

// ---------- fp8 e4m3fn round-to-nearest-even emulation (input pre-clipped to [-448,448]) ----------
__device__ __forceinline__ float fp8_round_rne(float x) {
    float ax = fabsf(x);
    if (ax < 0.015625f) {                 // below min normal 2^-6 -> subnormal grid 2^-9
        return rintf(x * 512.0f) * (1.0f / 512.0f);
    }
    unsigned u = __float_as_uint(x);
    const unsigned lsb = 1u << 20;        // keep top 3 mantissa bits of f32
    unsigned bias = (lsb >> 1) - 1u + ((u >> 20) & 1u);   // RNE
    u = (u + bias) & ~(lsb - 1u);
    return __uint_as_float(u);
}

__device__ __forceinline__ ushort_t f32_to_bf16_bits(float f) {
    unsigned u = __float_as_uint(f);
    unsigned r = u + 0x7FFFu + ((u >> 16) & 1u);          // RNE (exact for fp8-grid values)
    return (ushort_t)(r >> 16);
}

// ---------- quantize x: f32 -> fp8-rounded value stored as bf16 bits ----------
__global__ void quant_x_kernel(const float* __restrict__ x, ushort4v* __restrict__ out,
                               const float* __restrict__ in_scale, long n4) {
    const float s   = in_scale[0];
    const float inv = 1.0f / s;
    long i = (long)blockIdx.x * blockDim.x + threadIdx.x;
    const long stride = (long)gridDim.x * blockDim.x;
    for (; i < n4; i += stride) {
        float4v v = ((const float4v*)x)[i];
        ushort4v q;
#pragma unroll
        for (int j = 0; j < 4; ++j) {
            float t = v[j] * inv;
            t = fminf(fmaxf(t, -448.0f), 448.0f);
            t = fp8_round_rne(t);
            q[j] = f32_to_bf16_bits(t);
        }
        out[i] = q;
    }
}

// ---------- weight: values already exactly fp8-representable -> bf16 (exact) ----------
__global__ void quant_w_kernel(const float* __restrict__ w, ushort4v* __restrict__ out, long n4) {
    long i = (long)blockIdx.x * blockDim.x + threadIdx.x;
    const long stride = (long)gridDim.x * blockDim.x;
    for (; i < n4; i += stride) {
        float4v v = ((const float4v*)w)[i];
        ushort4v q;
#pragma unroll
        for (int j = 0; j < 4; ++j) q[j] = f32_to_bf16_bits(v[j]);
        out[i] = q;
    }
}

// ---------- bf16 GEMM: C[M,N] = A[M,K] * W[N,K]^T * sc + bias ----------
__global__ __launch_bounds__(256, 2) void gemm_kernel(
    const ushort_t* __restrict__ A,    // [M,K] bf16 bits
    const ushort_t* __restrict__ W,    // [N,K] bf16 bits
    const float*    __restrict__ bias, // [N] f32
    const float*    __restrict__ in_scale,
    const float*    __restrict__ w_scale,
    float*          __restrict__ C,    // [M,N] f32
    int M, int N, int K)
{
    __shared__ __align__(16) ushort_t sA[BM * BK];   // 16 KB, [128][64] linear, XOR-swizzled content
    __shared__ __align__(16) ushort_t sB[BN * BK];   // 16 KB

    const int tid  = threadIdx.x;
    const int wave = tid >> 6;
    const int lane = tid & 63;
    const int wr   = wave >> 1;   // wave row 0..1 (64 rows each)
    const int wc   = wave & 1;    // wave col 0..1 (64 cols each)

    // XCD-aware block swizzle (bijective: grid % 8 == 0 here)
    const int nwg = gridDim.x;
    int bid = blockIdx.x;
    int wgid;
    if ((nwg & 7) == 0) {
        const int cpx = nwg >> 3;
        wgid = (bid & 7) * cpx + (bid >> 3);
    } else {
        wgid = bid;
    }
    const int ntn  = N / BN;
    const int brow = (wgid / ntn) * BM;
    const int bcol = (wgid % ntn) * BN;

    // staging geometry: 16 chunks of 1KB per tile; wave w stages chunks 4w..4w+3
    // chunk c = rows c*8..c*8+7; lane i -> row c*8 + (i>>3), physical 16B slot (i&7)
    // read-side swizzle: slot' = slot ^ (row&7)  ==> source must fetch logical slot (i&7)^(i>>3)
    const int rowInChunk = lane >> 3;                 // 0..7  (== row & 7)
    const int slotLog    = (lane & 7) ^ rowInChunk;   // inverse-swizzled global slot

    f32x4 acc[4][4];
#pragma unroll
    for (int i = 0; i < 4; ++i)
#pragma unroll
        for (int j = 0; j < 4; ++j) {
            f32x4 z = {0.f, 0.f, 0.f, 0.f};
            acc[i][j] = z;
        }

    for (int kt = 0; kt < K; kt += BK) {
        if (kt) __syncthreads();
#pragma unroll
        for (int c = 0; c < 4; ++c) {
            const int chunk = wave * 4 + c;
            const int row   = chunk * 8 + rowInChunk;
            const ushort_t* ga = A + (long)(brow + row) * K + kt + slotLog * 8;
            const ushort_t* gb = W + (long)(bcol + row) * K + kt + slotLog * 8;
            __builtin_amdgcn_global_load_lds(
                (const __attribute__((address_space(1))) unsigned int*)ga,
                (__attribute__((address_space(3))) unsigned int*)(sA + chunk * 512),
                16, 0, 0);
            __builtin_amdgcn_global_load_lds(
                (const __attribute__((address_space(1))) unsigned int*)gb,
                (__attribute__((address_space(3))) unsigned int*)(sB + chunk * 512),
                16, 0, 0);
        }
        __syncthreads();

#pragma unroll
        for (int ks = 0; ks < BK; ks += 32) {
            bf16x8 af[4], bfr[4];
#pragma unroll
            for (int mi = 0; mi < 4; ++mi) {
                const int row = wr * 64 + mi * 16 + (lane & 15);
                int boff = row * 128 + ks * 2 + ((lane >> 4) << 4);
                boff ^= (row & 7) << 4;
                af[mi] = *(const bf16x8*)((const char*)sA + boff);
            }
#pragma unroll
            for (int ni = 0; ni < 4; ++ni) {
                const int row = wc * 64 + ni * 16 + (lane & 15);
                int boff = row * 128 + ks * 2 + ((lane >> 4) << 4);
                boff ^= (row & 7) << 4;
                bfr[ni] = *(const bf16x8*)((const char*)sB + boff);
            }
#pragma unroll
            for (int mi = 0; mi < 4; ++mi)
#pragma unroll
                for (int ni = 0; ni < 4; ++ni)
                    acc[mi][ni] = __builtin_amdgcn_mfma_f32_16x16x32_bf16(
                        af[mi], bfr[ni], acc[mi][ni], 0, 0, 0);
        }
    }

    // epilogue: out = acc * (s_in*s_w) + bias
    const float sc = in_scale[0] * w_scale[0];
#pragma unroll
    for (int ni = 0; ni < 4; ++ni) {
        const int n  = bcol + wc * 64 + ni * 16 + (lane & 15);
        const float bv = bias[n];
#pragma unroll
        for (int mi = 0; mi < 4; ++mi) {
            const int m0 = brow + wr * 64 + mi * 16 + ((lane >> 4) << 2);
#pragma unroll
            for (int r = 0; r < 4; ++r) {
                C[(long)(m0 + r) * N + n] = fmaf(acc[mi][ni][r], sc, bv);
            }
        }
    }
}

extern "C" void kernel_launch(void* const* d_in, const int* in_sizes, int n_in,
                              void* d_out, int out_size, void* d_ws, size_t ws_size,
                              hipStream_t stream) {
    const float* x    = (const float*)d_in[0];   // [B,S,IN] (f16 upcast to f32 by harness)
    const float* w    = (const float*)d_in[1];   // [OUT,IN]
    const float* bias = (const float*)d_in[2];   // [OUT]
    const float* in_s = (const float*)d_in[3];   // [1] f32
    const float* w_s  = (const float*)d_in[4];   // [1] f32
    float* out = (float*)d_out;                  // [B,S,OUT]

    const int  N   = in_sizes[2];                // OUT = 4096
    const long wsz = (long)in_sizes[1];          // OUT*IN
    const int  K   = (int)(wsz / N);             // IN = 4096
    const long xsz = (long)in_sizes[0];          // B*S*IN
    const int  M   = (int)(xsz / K);             // 8192

    ushort_t* xq = (ushort_t*)d_ws;              // M*K bf16
    ushort_t* wq = xq + (size_t)M * K;           // N*K bf16

    quant_x_kernel<<<4096, 256, 0, stream>>>(x, (ushort4v*)xq, in_s, xsz / 4);
    quant_w_kernel<<<2048, 256, 0, stream>>>(w, (ushort4v*)wq, wsz / 4);

    dim3 grid((M / BM) * (N / BN));              // 64*32 = 2048 blocks
    gemm_kernel<<<grid, 256, 0, stream>>>(xq, wq, bias, in_s, w_s, out, M, N, K);
}

// Round 4
// 212.678 us; speedup vs baseline: 1.5131x; 1.5131x over previous
//
#include <hip/hip_runtime.h>
#include <stdint.h>

typedef float  f32x4  __attribute__((ext_vector_type(4)));
typedef float  float4v __attribute__((ext_vector_type(4)));
typedef int    i32x4  __attribute__((ext_vector_type(4)));
typedef int    i32x8  __attribute__((ext_vector_type(8)));
typedef unsigned int u32x4 __attribute__((ext_vector_type(4)));

#define BM 128
#define BN 128
#define BK 128   // fp8 BYTES per K-tile row (128 elements)

// ---- f32 (pre-clamped to [-448,448]) -> OCP e4m3fn byte, RNE (matches ml_dtypes) ----
__device__ __forceinline__ unsigned f32_to_e4m3(float t) {
    unsigned u = __float_as_uint(t);
    unsigned s = (u >> 24) & 0x80u;            // sign -> bit7
    float ax = fabsf(t);
    if (ax < 0.015625f) {                      // below min normal 2^-6: subnormal grid 2^-9
        int m = (int)rintf(ax * 512.0f);       // 0..8 (8 rolls into exp=1 encoding)
        return s | (unsigned)m;
    }
    unsigned au = u & 0x7fffffffu;
    unsigned r = au + 0x7FFFFu + ((au >> 20) & 1u);   // RNE into top-3 mantissa bits
    return s | (((r >> 23) - 120u) << 3) | ((r >> 20) & 7u);
}

// ---- quantize x: f32 -> e4m3 bytes (16 elems / thread) ----
__global__ void quant_x_kernel(const float4v* __restrict__ x, u32x4* __restrict__ out,
                               const float* __restrict__ in_scale, long n16) {
    const float inv = 1.0f / in_scale[0];
    long i = (long)blockIdx.x * blockDim.x + threadIdx.x;
    const long stride = (long)gridDim.x * blockDim.x;
    for (; i < n16; i += stride) {
        u32x4 q;
#pragma unroll
        for (int j = 0; j < 4; ++j) {
            float4v v = x[i * 4 + j];
            unsigned p = 0;
#pragma unroll
            for (int e = 0; e < 4; ++e) {
                float t = fminf(fmaxf(v[e] * inv, -448.0f), 448.0f);
                p |= f32_to_e4m3(t) << (8 * e);
            }
            q[j] = p;
        }
        out[i] = q;
    }
}

// ---- weight: values already exactly e4m3-representable -> bytes (exact) ----
__global__ void quant_w_kernel(const float4v* __restrict__ w, u32x4* __restrict__ out, long n16) {
    long i = (long)blockIdx.x * blockDim.x + threadIdx.x;
    const long stride = (long)gridDim.x * blockDim.x;
    for (; i < n16; i += stride) {
        u32x4 q;
#pragma unroll
        for (int j = 0; j < 4; ++j) {
            float4v v = w[i * 4 + j];
            unsigned p = 0;
#pragma unroll
            for (int e = 0; e < 4; ++e) p |= f32_to_e4m3(v[e]) << (8 * e);
            q[j] = p;
        }
        out[i] = q;
    }
}

// ---- MX-fp8 GEMM: C[M,N] = A[M,K] * W[N,K]^T * sc + bias ----
// m97 sync structure (session-verified) + 16x16x128 f8f6f4 MFMA, unit block scales.
__global__ __launch_bounds__(256, 2) void gemm_kernel(
    const unsigned char* __restrict__ A,   // [M,K] e4m3 bytes
    const unsigned char* __restrict__ W,   // [N,K] e4m3 bytes
    const float* __restrict__ bias,
    const float* __restrict__ in_scale,
    const float* __restrict__ w_scale,
    float* __restrict__ C, int M, int N, int K)
{
    __shared__ __align__(16) unsigned char sA[BM * BK];  // 16 KB, [128 rows][128 B], swizzled content
    __shared__ __align__(16) unsigned char sB[BN * BK];  // 16 KB

    const int tid  = threadIdx.x;
    const int wave = tid >> 6;
    const int lane = tid & 63;
    const int wr   = wave >> 1;
    const int wc   = wave & 1;

    // XCD-aware bijective swizzle (2048 % 8 == 0)
    const int nwg = gridDim.x;
    int bid = blockIdx.x, wgid;
    if ((nwg & 7) == 0) { const int cpx = nwg >> 3; wgid = (bid & 7) * cpx + (bid >> 3); }
    else wgid = bid;
    const int ntn  = N / BN;
    const int brow = (wgid / ntn) * BM;
    const int bcol = (wgid % ntn) * BN;

    // staging: 16 chunks of 1KB per tile (8 rows x 128B); wave w stages chunks 4w..4w+3
    // phys 16B-slot p = lane&7 holds logical slot p ^ (row&7)  (pre-swizzled global source)
    const int rowInChunk = lane >> 3;                // == row & 7
    const int slotLog    = (lane & 7) ^ rowInChunk;  // inverse-swizzled source slot

    f32x4 acc[4][4];
#pragma unroll
    for (int i = 0; i < 4; ++i)
#pragma unroll
        for (int j = 0; j < 4; ++j) { f32x4 z = {0.f,0.f,0.f,0.f}; acc[i][j] = z; }

    const int g = lane >> 4;   // k-group 0..3: lane covers k bytes [g*32, g*32+32)

    for (int kt = 0; kt < K; kt += BK) {
        if (kt) __syncthreads();
#pragma unroll
        for (int c = 0; c < 4; ++c) {
            const int chunk = wave * 4 + c;
            const int row   = chunk * 8 + rowInChunk;
            const unsigned char* ga = A + (long)(brow + row) * K + kt + slotLog * 16;
            const unsigned char* gb = W + (long)(bcol + row) * K + kt + slotLog * 16;
            __builtin_amdgcn_global_load_lds(
                (const __attribute__((address_space(1))) unsigned int*)ga,
                (__attribute__((address_space(3))) unsigned int*)(sA + chunk * 1024), 16, 0, 0);
            __builtin_amdgcn_global_load_lds(
                (const __attribute__((address_space(1))) unsigned int*)gb,
                (__attribute__((address_space(3))) unsigned int*)(sB + chunk * 1024), 16, 0, 0);
        }
        __syncthreads();

        i32x8 af[4], bf[4];
#pragma unroll
        for (int mi = 0; mi < 4; ++mi) {
            const int row = wr * 64 + mi * 16 + (lane & 15);
            const int sw  = row & 7;
            const int s0  = (g << 1) ^ sw;            // physical slot of logical slot g*2
            const int s1  = ((g << 1) | 1) ^ sw;      // physical slot of logical slot g*2+1
            i32x4 lo = *(const i32x4*)(sA + row * 128 + s0 * 16);
            i32x4 hi = *(const i32x4*)(sA + row * 128 + s1 * 16);
            i32x8 t;
            t[0]=lo[0]; t[1]=lo[1]; t[2]=lo[2]; t[3]=lo[3];
            t[4]=hi[0]; t[5]=hi[1]; t[6]=hi[2]; t[7]=hi[3];
            af[mi] = t;
        }
#pragma unroll
        for (int ni = 0; ni < 4; ++ni) {
            const int row = wc * 64 + ni * 16 + (lane & 15);
            const int sw  = row & 7;
            const int s0  = (g << 1) ^ sw;
            const int s1  = ((g << 1) | 1) ^ sw;
            i32x4 lo = *(const i32x4*)(sB + row * 128 + s0 * 16);
            i32x4 hi = *(const i32x4*)(sB + row * 128 + s1 * 16);
            i32x8 t;
            t[0]=lo[0]; t[1]=lo[1]; t[2]=lo[2]; t[3]=lo[3];
            t[4]=hi[0]; t[5]=hi[1]; t[6]=hi[2]; t[7]=hi[3];
            bf[ni] = t;
        }

#pragma unroll
        for (int mi = 0; mi < 4; ++mi)
#pragma unroll
            for (int ni = 0; ni < 4; ++ni)
                acc[mi][ni] = __builtin_amdgcn_mfma_scale_f32_16x16x128_f8f6f4(
                    af[mi], bf[ni], acc[mi][ni],
                    0 /*cbsz: A fmt = fp8 e4m3*/, 0 /*blgp: B fmt = fp8 e4m3*/,
                    0, 0x7F7F7F7F /*A scales = 1.0*/,
                    0, 0x7F7F7F7F /*B scales = 1.0*/);
    }

    // epilogue: out = acc * (s_in*s_w) + bias   (C/D layout: col=lane&15, row=(lane>>4)*4+r)
    const float sc = in_scale[0] * w_scale[0];
#pragma unroll
    for (int ni = 0; ni < 4; ++ni) {
        const int n   = bcol + wc * 64 + ni * 16 + (lane & 15);
        const float bv = bias[n];
#pragma unroll
        for (int mi = 0; mi < 4; ++mi) {
            const int m0 = brow + wr * 64 + mi * 16 + ((lane >> 4) << 2);
#pragma unroll
            for (int r = 0; r < 4; ++r)
                C[(long)(m0 + r) * N + n] = fmaf(acc[mi][ni][r], sc, bv);
        }
    }
}

extern "C" void kernel_launch(void* const* d_in, const int* in_sizes, int n_in,
                              void* d_out, int out_size, void* d_ws, size_t ws_size,
                              hipStream_t stream) {
    const float* x    = (const float*)d_in[0];   // [B,S,IN] f32
    const float* w    = (const float*)d_in[1];   // [OUT,IN] f32 (e4m3-exact values)
    const float* bias = (const float*)d_in[2];   // [OUT]
    const float* in_s = (const float*)d_in[3];   // [1]
    const float* w_s  = (const float*)d_in[4];   // [1]
    float* out = (float*)d_out;                  // [B,S,OUT]

    const int  N   = in_sizes[2];                // 4096
    const long wsz = (long)in_sizes[1];
    const int  K   = (int)(wsz / N);             // 4096
    const long xsz = (long)in_sizes[0];
    const int  M   = (int)(xsz / K);             // 8192

    unsigned char* xq = (unsigned char*)d_ws;          // M*K e4m3 bytes (33.5 MB)
    unsigned char* wq = xq + (size_t)M * K;            // N*K e4m3 bytes (16.8 MB)

    quant_x_kernel<<<2048, 256, 0, stream>>>((const float4v*)x, (u32x4*)xq, in_s, xsz / 16);
    quant_w_kernel<<<2048, 256, 0, stream>>>((const float4v*)w, (u32x4*)wq, wsz / 16);

    dim3 grid((M / BM) * (N / BN));              // 64*32 = 2048 blocks, %8==0
    gemm_kernel<<<grid, 256, 0, stream>>>(xq, wq, bias, in_s, w_s, out, M, N, K);
}